// Round 8
// baseline (230.078 us; speedup 1.0000x reference)
//
#include <hip/hip_runtime.h>
#include <hip/hip_bf16.h>

#define NCLS 16
#define NBOX 2048
#define NTOT (NCLS * NBOX)
#define NCHUNK 32                 /* NBOX / 64 */
#define SCORE_THRESH 0.05f
#define NMS_THRESH 0.5f
#define DETS_PER_IMG 100
#define BBOX_CLIP 4.135166556742356f  /* log(1000/16) */

typedef unsigned long long u64;

// IoU identical (op order) to the reference; symmetric in the two boxes.
__device__ __forceinline__ float iou_f(float x1, float y1, float x2, float y2, float ar,
                                       float X1, float Y1, float X2, float Y2, float AR) {
#pragma clang fp contract(off)
    float lx = fmaxf(x1, X1);
    float ly = fmaxf(y1, Y1);
    float rx = fminf(x2, X2);
    float ry = fminf(y2, Y2);
    float w = fmaxf(rx - lx, 0.0f);
    float h = fmaxf(ry - ly, 0.0f);
    float inter = w * h;
    return inter / (ar + AR - inter + 1e-12f);
}

__device__ __forceinline__ u64 sel_mx(u64 a, u64 b, bool keepmax) {
    u64 mx = (a > b) ? a : b;
    u64 mn = (a > b) ? b : a;
    return keepmax ? mx : mn;
}

// ---------------- Kernel 1: fused decode + register-resident bitonic sort ----
__global__ __launch_bounds__(1024) void sortdecode_kernel(
    const float* __restrict__ logits,   // (NTOT, 2)
    const float* __restrict__ regr,     // (NTOT, 8)
    const float* __restrict__ props,    // (NBOX, 4)
    float4* __restrict__ dec,           // (NTOT)
    u64* __restrict__ keys_out,         // (NTOT)
    float4* __restrict__ sbox4,         // (NTOT) sorted boxes
    float* __restrict__ sarea)          // (NTOT) sorted areas
{
    int c = blockIdx.x;
    int tid = threadIdx.x;
    int w = tid >> 6, l = tid & 63;
    int p0 = w * 128 + l;
    int p1 = p0 + 64;
    __shared__ u64 sk[NBOX];

    u64 e01[2];
#pragma unroll
    for (int s = 0; s < 2; s++) {
#pragma clang fp contract(off)
        int t = s ? p1 : p0;
        int i = c * NBOX + t;
        float x0 = logits[2 * i + 0];
        float x1 = logits[2 * i + 1];
        float m = fmaxf(x0, x1);
        float e0f = expf(x0 - m);
        float e1f = expf(x1 - m);
        float score = e1f / (e0f + e1f);

        float px1 = props[4 * t + 0];
        float py1 = props[4 * t + 1];
        float px2 = props[4 * t + 2];
        float py2 = props[4 * t + 3];

        float bw = px2 - px1 + 1.0f;
        float bh = py2 - py1 + 1.0f;
        float cx = px1 + 0.5f * bw;
        float cy = py1 + 0.5f * bh;

        float dx = regr[8 * i + 4] / 10.0f;
        float dy = regr[8 * i + 5] / 10.0f;
        float dw = fminf(regr[8 * i + 6] / 5.0f, BBOX_CLIP);
        float dh = fminf(regr[8 * i + 7] / 5.0f, BBOX_CLIP);

        float pcx = dx * bw + cx;
        float pcy = dy * bh + cy;
        float pw  = expf(dw) * bw;
        float ph  = expf(dh) * bh;

        float b0 = pcx - 0.5f * pw;
        float b1 = pcy - 0.5f * ph;
        float b2 = pcx + 0.5f * pw - 1.0f;
        float b3 = pcy + 0.5f * ph - 1.0f;

        b0 = fminf(fmaxf(b0, 0.0f), 1332.0f);
        b1 = fminf(fmaxf(b1, 0.0f), 799.0f);
        b2 = fminf(fmaxf(b2, 0.0f), 1332.0f);
        b3 = fminf(fmaxf(b3, 0.0f), 799.0f);

        dec[i] = make_float4(b0, b1, b2, b3);

        unsigned mono = 0u;
        if (score > SCORE_THRESH) mono = __float_as_uint(score) | 0x80000000u;
        e01[s] = ((u64)mono << 32) | (u64)(unsigned)(NBOX - 1 - t);
    }
    u64 e0 = e01[0], e1 = e01[1];

    for (int k = 2; k <= NBOX; k <<= 1) {
        bool desc0 = (p0 & k) == 0;
        bool desc1 = (p1 & k) == 0;
        for (int j = k >> 1; j > 0; j >>= 1) {
            if (j >= 128) {
                sk[p0] = e0; sk[p1] = e1;
                __syncthreads();
                u64 q0 = sk[p0 ^ j];
                u64 q1 = sk[p1 ^ j];
                e0 = sel_mx(e0, q0, desc0 ^ ((p0 & j) != 0));
                e1 = sel_mx(e1, q1, desc1 ^ ((p1 & j) != 0));
                __syncthreads();
            } else if (j == 64) {
                u64 mx = (e0 > e1) ? e0 : e1;
                u64 mn = (e0 > e1) ? e1 : e0;
                e0 = desc0 ? mx : mn;
                e1 = desc0 ? mn : mx;
            } else {
                u64 q0 = __shfl_xor(e0, j);
                u64 q1 = __shfl_xor(e1, j);
                bool hi = (l & j) != 0;
                e0 = sel_mx(e0, q0, desc0 ^ hi);
                e1 = sel_mx(e1, q1, desc1 ^ hi);
            }
        }
    }

    sk[p0] = e0; sk[p1] = e1;
    __syncthreads();

    for (int t = tid; t < NBOX; t += 1024) {
        u64 key = sk[t];
        keys_out[c * NBOX + t] = key;
        int idx = (NBOX - 1) - (int)(key & 0xFFFFFFFFull);
        int orig = c * NBOX + idx;
        float4 b = dec[orig];
        sbox4[c * NBOX + t] = b;
        {
#pragma clang fp contract(off)
            sarea[c * NBOX + t] = (b.z - b.x) * (b.w - b.y);
        }
    }
}

// ---------------- Kernel 2: transposed IoU bitmask ----------------
// maskT[c][I][j] = u64 over rows i2 of chunk I: bit set iff global row
// (I*64+i2) < j && IoU > thresh. Zero-filled for I > chunk(j) so the
// resolve kernel's fixed-trip update sweep reads defined data.
__global__ __launch_bounds__(256) void mask_kernel(
    const float4* __restrict__ sbox4,
    const float* __restrict__ sarea,
    u64* __restrict__ maskT)
{
    int c = blockIdx.x >> 4;
    int p = blockIdx.x & 15;
    __shared__ float4 box[NBOX];   // 32 KB
    __shared__ float  area[NBOX];  // 8 KB

    for (int i = threadIdx.x; i < NBOX; i += 256) {
        box[i]  = sbox4[c * NBOX + i];
        area[i] = sarea[c * NBOX + i];
    }
    __syncthreads();

    int r = threadIdx.x & 63;   // column lane
    int g = threadIdx.x >> 6;   // row-chunk group

    for (int pass = 0; pass < 2; pass++) {
        int Jc = pass ? (31 - p) : p;     // column chunk (balanced pairing)
        int j = Jc * 64 + r;              // global sorted column index
        float4 jb = box[j];
        float jar = area[j];

        for (int I = g; I < NCHUNK; I += 4) {
            u64 w = 0;
            if (I <= Jc) {
                int rbase = I * 64;
#pragma unroll 8
                for (int i2 = 0; i2 < 64; i2++) {
                    int gi = rbase + i2;
                    float4 rb = box[gi];           // wave-uniform -> LDS broadcast
                    float iou = iou_f(rb.x, rb.y, rb.z, rb.w, area[gi],
                                      jb.x, jb.y, jb.z, jb.w, jar);
                    if (gi < j && iou > NMS_THRESH) w |= 1ull << i2;
                }
            }
            maskT[((size_t)c * NCHUNK + I) * NBOX + j] = w;   // coalesced in j
        }
    }
}

// ---------------- Kernel 3: barrier-free single-wave greedy resolve ----------
// One wave per class. Lane ln owns columns {s*64+ln, s=0..31}; validity /
// suppressed / kept are per-lane register bitmasks. Per chunk: in-wave ballot
// transpose scan on the prefetched diag word, then a fully-unrolled 31-load
// update sweep (independent coalesced loads, one waitcnt). No LDS, no barriers.
__global__ __launch_bounds__(64) void resolve_kernel(
    const u64* __restrict__ keys,
    const u64* __restrict__ maskT,
    unsigned* __restrict__ keepbits)
{
    int c = blockIdx.x;
    int ln = threadIdx.x;
    const u64* MT = maskT + (size_t)c * NCHUNK * NBOX;
    const u64* K  = keys + (size_t)c * NBOX;

    unsigned valid_bits = 0;
#pragma unroll
    for (int s = 0; s < NCHUNK; s++) {
        u64 k = K[s * 64 + ln];
        valid_bits |= (((unsigned)(k >> 32) != 0u) ? 1u : 0u) << s;
    }

    u64 diagA = MT[ln];   // chunk 0 diag word (I=0, j=ln)
    unsigned sup_bits = 0, kept_bits = 0;

    for (int I = 0; I < NCHUNK; I++) {
        u64 diagB = 0;
        if (I + 1 < NCHUNK)
            diagB = MT[(size_t)(I + 1) * NBOX + (I + 1) * 64 + ln];

        // greedy scan of chunk I (wave-uniform)
        bool av = ((valid_bits >> I) & 1u) && !((sup_bits >> I) & 1u);
        u64 avail = __ballot(av);
        u64 kept = 0;
#pragma unroll
        for (int i = 0; i < 64; i++) {
            u64 row = __ballot((diagA >> i) & 1ull);   // in-wave bit transpose
            if ((avail >> i) & 1ull) { kept |= 1ull << i; avail &= ~row; }
        }
        kept_bits |= (unsigned)((kept >> ln) & 1ull) << I;

        // update sweep: fixed trip, independent coalesced loads
        const u64* MR = MT + (size_t)I * NBOX + ln;
#pragma unroll
        for (int s = 1; s < NCHUNK; s++) {
            u64 w = MR[s * 64];           // zero for s < I (zero-filled), harmless
            if (w & kept) sup_bits |= 1u << s;
        }
        diagA = diagB;
    }

#pragma unroll
    for (int s = 0; s < NCHUNK; s++) {
        u64 k = K[s * 64 + ln];
        unsigned mono = (unsigned)(k >> 32);
        int orig = c * NBOX + (NBOX - 1) - (int)(k & 0xFFFFFFFFull);
        keepbits[orig] = ((kept_bits >> s) & 1u) ? (mono & 0x7FFFFFFFu) : 0u;
    }
}

// ---------------- Kernel 4: count + exact 3-pass radix-select of kth ----------------
__global__ __launch_bounds__(1024) void select_kernel(
    const unsigned* __restrict__ keepbits,
    int* __restrict__ stats)   // stats[0]=n_det, stats[1]=kth bits
{
    __shared__ int hist[2048];
    __shared__ int gsum[64];
    __shared__ int s_cnt;
    __shared__ unsigned s_prefix;
    __shared__ int s_rank;
    int tid = threadIdx.x;
    const uint4* kb4 = (const uint4*)keepbits;

    for (int b = tid; b < 2048; b += 1024) hist[b] = 0;
    if (tid == 0) s_cnt = 0;
    __syncthreads();
    int cnt = 0;
    for (int i = tid; i < NTOT / 4; i += 1024) {
        uint4 v = kb4[i];
        if (v.x) { cnt++; atomicAdd(&hist[v.x >> 21], 1); }
        if (v.y) { cnt++; atomicAdd(&hist[v.y >> 21], 1); }
        if (v.z) { cnt++; atomicAdd(&hist[v.z >> 21], 1); }
        if (v.w) { cnt++; atomicAdd(&hist[v.w >> 21], 1); }
    }
    atomicAdd(&s_cnt, cnt);
    __syncthreads();
    int n_det = s_cnt;

    if (n_det > DETS_PER_IMG) {
        if (tid < 64) {
            int s = 0;
            for (int t = 0; t < 32; t++) s += hist[tid * 32 + t];
            gsum[tid] = s;
        }
        __syncthreads();
        if (tid == 0) {
            int r = DETS_PER_IMG;
            int g = 63;
            for (; g > 0; g--) { if (r <= gsum[g]) break; r -= gsum[g]; }
            int b = g * 32 + 31;
            for (; b > g * 32; b--) { if (r <= hist[b]) break; r -= hist[b]; }
            s_prefix = (unsigned)b << 21;
            s_rank = r;
        }
        __syncthreads();

        unsigned p1 = s_prefix;
        for (int b = tid; b < 2048; b += 1024) hist[b] = 0;
        __syncthreads();
        for (int i = tid; i < NTOT / 4; i += 1024) {
            uint4 v = kb4[i];
            if (v.x && (v.x >> 21 << 21) == p1) atomicAdd(&hist[(v.x >> 10) & 2047], 1);
            if (v.y && (v.y >> 21 << 21) == p1) atomicAdd(&hist[(v.y >> 10) & 2047], 1);
            if (v.z && (v.z >> 21 << 21) == p1) atomicAdd(&hist[(v.z >> 10) & 2047], 1);
            if (v.w && (v.w >> 21 << 21) == p1) atomicAdd(&hist[(v.w >> 10) & 2047], 1);
        }
        __syncthreads();
        if (tid < 64) {
            int s = 0;
            for (int t = 0; t < 32; t++) s += hist[tid * 32 + t];
            gsum[tid] = s;
        }
        __syncthreads();
        if (tid == 0) {
            int r = s_rank;
            int g = 63;
            for (; g > 0; g--) { if (r <= gsum[g]) break; r -= gsum[g]; }
            int b = g * 32 + 31;
            for (; b > g * 32; b--) { if (r <= hist[b]) break; r -= hist[b]; }
            s_prefix = p1 | ((unsigned)b << 10);
            s_rank = r;
        }
        __syncthreads();

        unsigned p2 = s_prefix;
        for (int b = tid; b < 1024; b += 1024) hist[b] = 0;
        __syncthreads();
        for (int i = tid; i < NTOT / 4; i += 1024) {
            uint4 v = kb4[i];
            if (v.x && (v.x >> 10 << 10) == p2) atomicAdd(&hist[v.x & 1023], 1);
            if (v.y && (v.y >> 10 << 10) == p2) atomicAdd(&hist[v.y & 1023], 1);
            if (v.z && (v.z >> 10 << 10) == p2) atomicAdd(&hist[v.z & 1023], 1);
            if (v.w && (v.w >> 10 << 10) == p2) atomicAdd(&hist[v.w & 1023], 1);
        }
        __syncthreads();
        if (tid < 32) {
            int s = 0;
            for (int t = 0; t < 32; t++) s += hist[tid * 32 + t];
            gsum[tid] = s;
        }
        __syncthreads();
        if (tid == 0) {
            int r = s_rank;
            int g = 31;
            for (; g > 0; g--) { if (r <= gsum[g]) break; r -= gsum[g]; }
            int b = g * 32 + 31;
            for (; b > g * 32; b--) { if (r <= hist[b]) break; r -= hist[b]; }
            s_prefix = p2 | (unsigned)b;
        }
        __syncthreads();
    }

    if (tid == 0) {
        stats[0] = n_det;
        stats[1] = (n_det > DETS_PER_IMG) ? (int)s_prefix : 0;
    }
}

// ---------------- Kernel 5: final outputs ----------------
__global__ __launch_bounds__(256) void write_kernel(
    const unsigned* __restrict__ keepbits,
    const float4* __restrict__ dec,
    const int* __restrict__ stats,
    const int* __restrict__ ulabels,
    float* __restrict__ out)
{
    int i = blockIdx.x * blockDim.x + threadIdx.x;
    if (i >= NTOT) return;

    int n_det = stats[0];
    unsigned kth = (unsigned)stats[1];
    unsigned kb = keepbits[i];
    bool kf = kb && (n_det <= DETS_PER_IMG || kb >= kth);  // uint cmp == float cmp (positive)

    float4 b = dec[i];
    float* o5 = out + (size_t)i * 5;
    if (kf) {
        o5[0] = b.x; o5[1] = b.y; o5[2] = b.z; o5[3] = b.w;
        o5[4] = __uint_as_float(kb);
    } else {
        o5[0] = 0.0f; o5[1] = 0.0f; o5[2] = 0.0f; o5[3] = 0.0f; o5[4] = 0.0f;
    }

    int c = i >> 11;
    out[NTOT * 5 + i] = (float)ulabels[c];
    out[NTOT * 5 + NTOT + i] = kf ? 1.0f : 0.0f;
}

extern "C" void kernel_launch(void* const* d_in, const int* in_sizes, int n_in,
                              void* d_out, int out_size, void* d_ws, size_t ws_size,
                              hipStream_t stream) {
    (void)in_sizes; (void)n_in; (void)out_size; (void)ws_size;

    const float* class_logit    = (const float*)d_in[0];   // (NTOT,2)
    const float* box_regression = (const float*)d_in[1];   // (NTOT,8)
    const float* proposal_boxes = (const float*)d_in[2];   // (NBOX,4)
    const int*   unique_labels  = (const int*)d_in[3];     // (NCLS)

    char* ws = (char*)d_ws;
    float4* dec        = (float4*)(ws + 0);         // 524288
    u64* keys          = (u64*)(ws + 524288);       // 262144
    float4* sbox4      = (float4*)(ws + 786432);    // 524288
    float* sarea       = (float*)(ws + 1310720);    // 131072
    unsigned* keepbits = (unsigned*)(ws + 1441792); // 131072
    int* stats         = (int*)(ws + 1572864);      // 256
    u64* maskT         = (u64*)(ws + 1573120);      // 8388608

    float* out = (float*)d_out;

    sortdecode_kernel<<<NCLS, 1024, 0, stream>>>(class_logit, box_regression,
                                                 proposal_boxes, dec, keys,
                                                 sbox4, sarea);
    mask_kernel<<<NCLS * 16, 256, 0, stream>>>(sbox4, sarea, maskT);
    resolve_kernel<<<NCLS, 64, 0, stream>>>(keys, maskT, keepbits);
    select_kernel<<<1, 1024, 0, stream>>>(keepbits, stats);
    write_kernel<<<NTOT / 256, 256, 0, stream>>>(keepbits, dec, stats,
                                                 unique_labels, out);
}